// Round 12
// baseline (420.578 us; speedup 1.0000x reference)
//
#include <hip/hip_runtime.h>
#include <math.h>

#define N_NODES 8192
#define N_EDGES 262144
#define INV_SQRT3 0.5773502691896258f

typedef __attribute__((ext_vector_type(8))) _Float16 half8;
typedef __attribute__((ext_vector_type(4))) _Float16 half4;
typedef __attribute__((ext_vector_type(4))) float floatx4;

#define MF16(a,b,c) __builtin_amdgcn_mfma_f32_16x16x32_f16(a,b,c,0,0,0)

__device__ __forceinline__ float sspf(float x){
    // softplus(x) - ln2 via hw v_exp/v_log
    return (x > 20.0f) ? (x - 0.69314718f)
                       : (__logf(1.0f + __expf(x)) - 0.69314718f);
}

// ---------------------------------------------------------------------------
// Node kernel (factored sc einsum): sc = einsum('nu,nuv->nv', s, T),
// T[n,u,v] = einsum('na,uav->nuv', attrs, Ws). 4 nodes/block.
// Also computes q, qd (= Wd^T q, scales folded), stored PERMUTED:
// qdbuf[n][col*8+slot], slot = {qd0[c], qd0[c+16], qd1[3c..+2], qd1[3(c+16)..+2]}.
// ---------------------------------------------------------------------------
__global__ __launch_bounds__(256) void node_kernel(
    const float* __restrict__ feats, const float* __restrict__ attrs,
    const float* __restrict__ Wq0, const float* __restrict__ Wq1,
    const float* __restrict__ Wd0, const float* __restrict__ Wd1,
    const float* __restrict__ Ws0, const float* __restrict__ Ws1,
    float* __restrict__ qdbuf, float* __restrict__ out)
{
    __shared__ float sa[4][16];
    __shared__ float sT[4][4][32];
    __shared__ float Tl[2][4][1152];   // T, rows stride 36
    __shared__ float qT[4][4][32];
    __shared__ float qsh[4][128];

    const int t  = threadIdx.x;
    const int nb = blockIdx.x * 4;

    const float inv_sqrt32 = 0.17677669529663687f;
    const float sc_scale   = 0.04419417382415922f;
    const float d_scale    = 0.022097086912079608f;

    for (int i = t; i < 512; i += 256){
        int nn = i >> 7, r = i & 127;
        int p = r >> 5, u = r & 31;
        sT[nn][p][u] = feats[(size_t)(nb+nn)*128 + ((p==0) ? u : 32 + u*3 + (p-1))];
    }
    if (t < 64) sa[t>>4][t&15] = attrs[(size_t)(nb + (t>>4))*16 + (t&15)];
    __syncthreads();

    const int v  = t & 31;
    const int g5 = (t >> 5) & 3;
    const int hi = t >> 7;

    {
        const float* __restrict__ Wm = hi ? Ws1 : Ws0;
        float sar[4][16];
        #pragma unroll
        for (int nn = 0; nn < 4; ++nn)
            #pragma unroll
            for (int a = 0; a < 16; ++a) sar[nn][a] = sa[nn][a];
        #pragma unroll
        for (int uu = 0; uu < 8; ++uu){
            int u = g5*8 + uu;
            float a0=0.f, a1=0.f, a2=0.f, a3=0.f;
            #pragma unroll
            for (int a = 0; a < 16; ++a){
                float w = Wm[(u*16 + a)*32 + v];
                a0 += sar[0][a]*w; a1 += sar[1][a]*w;
                a2 += sar[2][a]*w; a3 += sar[3][a]*w;
            }
            Tl[hi][0][v*36+u] = a0; Tl[hi][1][v*36+u] = a1;
            Tl[hi][2][v*36+u] = a2; Tl[hi][3][v*36+u] = a3;
        }
    }
    __syncthreads();

    const int p  = g5;
    const int n0 = hi*2, n1 = n0 + 1;
    const int mm = (p==0) ? 0 : 1;
    const float* __restrict__ Wqp = (p==0) ? Wq0 : Wq1;
    const float* __restrict__ Wdp = (p==0) ? Wd0 : Wd1;
    const int oidx = (p==0) ? v : 32 + v*3 + (p-1);

    float c0=0.f, c1=0.f;
    #pragma unroll
    for (int uc = 0; uc < 8; ++uc){
        float4 t0 = *(const float4*)&Tl[mm][n0][v*36 + uc*4];
        float4 t1 = *(const float4*)&Tl[mm][n1][v*36 + uc*4];
        float4 s0 = *(const float4*)&sT[n0][p][uc*4];
        float4 s1 = *(const float4*)&sT[n1][p][uc*4];
        c0 += t0.x*s0.x + t0.y*s0.y + t0.z*s0.z + t0.w*s0.w;
        c1 += t1.x*s1.x + t1.y*s1.y + t1.z*s1.z + t1.w*s1.w;
    }
    out[(size_t)(nb+n0)*128 + oidx] = c0 * sc_scale;
    out[(size_t)(nb+n1)*128 + oidx] = c1 * sc_scale;

    float q0=0.f, q1=0.f;
    #pragma unroll
    for (int u = 0; u < 32; ++u){
        float w = Wqp[u*32 + v];
        q0 += sT[n0][p][u] * w;
        q1 += sT[n1][p][u] * w;
    }
    qT[n0][p][v] = q0 * inv_sqrt32;
    qT[n1][p][v] = q1 * inv_sqrt32;
    __syncthreads();

    float d0=0.f, d1=0.f;
    #pragma unroll
    for (int u = 0; u < 32; ++u){
        float w = Wdp[u*32 + v];
        d0 += qT[n0][p][u] * w;
        d1 += qT[n1][p][u] * w;
    }
    float dsc = (p==0) ? d_scale : d_scale * INV_SQRT3;
    qsh[n0][oidx] = d0 * dsc;
    qsh[n1][oidx] = d1 * dsc;
    __syncthreads();

    for (int i = t; i < 512; i += 256){
        int nn = i >> 7, tt = i & 127;
        int col = tt >> 3, slot = tt & 7;
        int src;
        if      (slot == 0) src = col;
        else if (slot == 1) src = col + 16;
        else if (slot <  5) src = 32 + 3*col + (slot-2);
        else                src = 32 + 3*(col+16) + (slot-5);
        qdbuf[(size_t)(nb+nn)*128 + tt] = qsh[nn][src];
    }
}

// ---------------------------------------------------------------------------
// fp16 conversion of gathered streams: feats (1M fl), emb (4M), eattr (1M).
// One float4 -> half4 per thread; 1572864 float4 total -> 6144 blocks.
// ---------------------------------------------------------------------------
__global__ __launch_bounds__(256) void convert_kernel(
    const float* __restrict__ feats, const float* __restrict__ emb,
    const float* __restrict__ eattr,
    _Float16* __restrict__ feats16, _Float16* __restrict__ emb16,
    _Float16* __restrict__ eattr16)
{
    int idx = blockIdx.x*256 + threadIdx.x;
    const float* src; _Float16* dst; int off;
    if (idx < 262144)            { src = feats; dst = feats16; off = idx; }
    else if (idx < 1310720)      { src = emb;   dst = emb16;   off = idx - 262144; }
    else                         { src = eattr; dst = eattr16; off = idx - 1310720; }
    float4 v = *(const float4*)(src + (size_t)off*4);
    half4 h;
    h[0]=(_Float16)v.x; h[1]=(_Float16)v.y; h[2]=(_Float16)v.z; h[3]=(_Float16)v.w;
    *(half4*)(dst + (size_t)off*4) = h;
}

// ---------------------------------------------------------------------------
// CSR build: histogram by dst -> exclusive scan -> scatter permutation.
// ---------------------------------------------------------------------------
__global__ __launch_bounds__(256) void count_kernel(
    const int* __restrict__ eidx, int* __restrict__ degb)
{
    int e = blockIdx.x*256 + threadIdx.x;
    atomicAdd(&degb[eidx[N_EDGES + e]], 1);
}

__global__ __launch_bounds__(256) void scan_kernel(
    const int* __restrict__ degb, int* __restrict__ rowstart,
    int* __restrict__ cursor)
{
    __shared__ int part[256];
    int t = threadIdx.x;
    int loc[32];
    int s = 0;
    #pragma unroll
    for (int i = 0; i < 32; ++i){ loc[i] = s; s += degb[t*32 + i]; }
    part[t] = s;
    __syncthreads();
    for (int d = 1; d < 256; d <<= 1){
        int v = (t >= d) ? part[t-d] : 0;
        __syncthreads();
        part[t] += v;
        __syncthreads();
    }
    int excl = part[t] - s;
    #pragma unroll
    for (int i = 0; i < 32; ++i){
        int v = excl + loc[i];
        rowstart[t*32 + i] = v;
        cursor[t*32 + i]   = v;
    }
    if (t == 255) rowstart[N_NODES] = excl + s;
}

__global__ __launch_bounds__(256) void scatter_kernel(
    const int* __restrict__ eidx, int* __restrict__ cursor,
    int* __restrict__ perm)
{
    int e = blockIdx.x*256 + threadIdx.x;
    int p = atomicAdd(&cursor[eidx[N_EDGES + e]], 1);
    perm[p] = e;
}

// ---------------------------------------------------------------------------
// Node-centric MFMA edge pass. fp16 gathered inputs (feats16/emb16/eattr16)
// halve the dominant L2-miss gather traffic (R11: FETCH=157MB matched
// 512B/edge feats + emb + eattr). fL0/fL1 weight fragments live in REGISTERS
// (8 named half8 = 32 VGPR): LDS = 4096(fW1)+16384(fW2)+17408(stag)=37888 B
// -> 4 blocks/CU = 16 waves. NO atomics.
// mfma_f32_16x16x32_f16 layouts (measured, learn_hip m89/m120):
// A[m=lane&15][k=quad*8+j]; B[k=quad*8+j][n=lane&15]; C col=lane&15,
// row=quad*4+reg.
// ---------------------------------------------------------------------------
template<int PASS>
__global__ __launch_bounds__(256, 4) void edge_pass(
    const _Float16* __restrict__ feats16, const _Float16* __restrict__ emb16,
    const _Float16* __restrict__ eattr16, const int* __restrict__ eidx,
    const float* __restrict__ W1,  const float* __restrict__ W2,
    const float* __restrict__ WL0, const float* __restrict__ WL1,
    const float* __restrict__ qdbuf,
    const int* __restrict__ rowstart, const int* __restrict__ perm,
    float* __restrict__ cfbuf, float* __restrict__ zbuf,
    float* __restrict__ out)
{
    __shared__ half8 fW1[4][64];
    __shared__ half8 fW2[16][64];
    __shared__ _Float16 stag[4][16][136];

    const int t    = threadIdx.x;
    const int lane = t & 63;
    const int col  = lane & 15;
    const int quad = lane >> 4;
    const int g    = t >> 6;

    // ---- fW1/fW2 into LDS (scales folded) ----
    {
        half8 f;
        #pragma unroll
        for (int j = 0; j < 8; ++j){
            int k = quad*8 + j;
            f[j] = (k < 16) ? (_Float16)(W1[k*64 + g*16 + col] * 0.25f) : (_Float16)0.f;
        }
        fW1[g][lane] = f;
    }
    #pragma unroll
    for (int ff = 0; ff < 4; ++ff){
        int fr = g*4 + ff, tile = fr >> 1, s = fr & 1;
        half8 f;
        #pragma unroll
        for (int j = 0; j < 8; ++j)
            f[j] = (_Float16)(W2[(s*32 + quad*8 + j)*128 + tile*16 + col] * 0.125f);
        fW2[fr][lane] = f;
    }
    // ---- fL0/fL1 fragments into REGISTERS (loop-invariant, named) ----
    half8 rL00, rL01, rL02, rL03, rL10, rL11, rL12, rL13;
    #pragma unroll
    for (int j = 0; j < 8; ++j){
        int kA = (quad*8 + j)*32;          // s=0
        int kB = (32 + quad*8 + j)*32;     // s=1
        rL00[j] = (_Float16)(WL0[kA + col]      * 0.125f);
        rL01[j] = (_Float16)(WL0[kB + col]      * 0.125f);
        rL02[j] = (_Float16)(WL0[kA + 16 + col] * 0.125f);
        rL03[j] = (_Float16)(WL0[kB + 16 + col] * 0.125f);
        rL10[j] = (_Float16)(WL1[kA + col]      * 0.125f);
        rL11[j] = (_Float16)(WL1[kB + col]      * 0.125f);
        rL12[j] = (_Float16)(WL1[kA + 16 + col] * 0.125f);
        rL13[j] = (_Float16)(WL1[kB + 16 + col] * 0.125f);
    }
    __syncthreads();     // the only block-wide barrier

    const floatx4 zzero = {0.f, 0.f, 0.f, 0.f};

    const int n  = blockIdx.x*4 + g;
    const int r0 = rowstart[n];
    const int dcount = rowstart[n+1] - r0;

    float4 qa, qb;
    if (PASS == 1){
        const float* qdp = qdbuf + (size_t)n*128 + col*8;
        qa = *(const float4*)qdp;
        qb = *(const float4*)(qdp + 4);
    }
    float rz = 0.f;
    if (PASS == 2){
        float z = zbuf[n];
        rz = (z > 0.f) ? rsqrtf(z) : 0.f;
    }

    float macc0=0.f, macc1=0.f, macc2=0.f, macc3=0.f;
    float macc4=0.f, macc5=0.f, macc6=0.f, macc7=0.f;
    float zacc = 0.f;

    for (int tb = 0; tb < dcount; tb += 16){
        int slot = tb + col;
        int eA = perm[r0 + ((slot < dcount) ? slot : (dcount-1))];

        // ---- A-fragment: emb16 rows, direct half8 (K=16 padded to 32) ----
        half8 ea;
        if (quad < 2){
            ea = *(const half8*)(emb16 + (size_t)eA*16 + quad*8);
        } else {
            #pragma unroll
            for (int j = 0; j < 8; ++j) ea[j] = (_Float16)0.f;
        }

        const int srcm = eidx[eA];
        const _Float16* fsrc = feats16 + (size_t)srcm*128;
        half4 hy = *(const half4*)(eattr16 + (size_t)eA*4);
        const float y0 = (float)hy[0], y1a = (float)hy[1],
                    y1b = (float)hy[2], y1c = (float)hy[3];

        half8 hx = *(const half8*)(fsrc + quad*8);
        float xs0[8];
        #pragma unroll
        for (int j = 0; j < 8; ++j) xs0[j] = (float)hx[j];
        half8 hz0 = *(const half8*)(fsrc + 32 + quad*24);
        half8 hz1 = *(const half8*)(fsrc + 32 + quad*24 + 8);
        half8 hz2 = *(const half8*)(fsrc + 32 + quad*24 + 16);
        float x1s[24];
        #pragma unroll
        for (int j = 0; j < 8; ++j){
            x1s[j]      = (float)hz0[j];
            x1s[8 + j]  = (float)hz1[j];
            x1s[16 + j] = (float)hz2[j];
        }

        // ---- GEMM1 -> ssp -> h staging ----
        floatx4 hA = MF16(ea, fW1[0][lane], zzero);
        floatx4 hB = MF16(ea, fW1[1][lane], zzero);
        floatx4 hC = MF16(ea, fW1[2][lane], zzero);
        floatx4 hD = MF16(ea, fW1[3][lane], zzero);
        #pragma unroll
        for (int r = 0; r < 4; ++r){
            stag[g][quad*4+r][   col] = (_Float16)sspf(hA[r]);
            stag[g][quad*4+r][16+col] = (_Float16)sspf(hB[r]);
            stag[g][quad*4+r][32+col] = (_Float16)sspf(hC[r]);
            stag[g][quad*4+r][48+col] = (_Float16)sspf(hD[r]);
        }
        half8 a0 = *(const half8*)&stag[g][col][quad*8];
        half8 a1 = *(const half8*)&stag[g][col][32 + quad*8];

        // ---- GEMM2: w = h @ W2 (writes overlay h; same-wave DS in-order) ----
        floatx4 wc0 = MF16(a0, fW2[ 0][lane], zzero); wc0 = MF16(a1, fW2[ 1][lane], wc0);
        floatx4 wc1 = MF16(a0, fW2[ 2][lane], zzero); wc1 = MF16(a1, fW2[ 3][lane], wc1);
        floatx4 wc2 = MF16(a0, fW2[ 4][lane], zzero); wc2 = MF16(a1, fW2[ 5][lane], wc2);
        floatx4 wc3 = MF16(a0, fW2[ 6][lane], zzero); wc3 = MF16(a1, fW2[ 7][lane], wc3);
        floatx4 wc4 = MF16(a0, fW2[ 8][lane], zzero); wc4 = MF16(a1, fW2[ 9][lane], wc4);
        floatx4 wc5 = MF16(a0, fW2[10][lane], zzero); wc5 = MF16(a1, fW2[11][lane], wc5);
        floatx4 wc6 = MF16(a0, fW2[12][lane], zzero); wc6 = MF16(a1, fW2[13][lane], wc6);
        floatx4 wc7 = MF16(a0, fW2[14][lane], zzero); wc7 = MF16(a1, fW2[15][lane], wc7);
        #pragma unroll
        for (int r = 0; r < 4; ++r){
            stag[g][quad*4+r][  0+col] = (_Float16)wc0[r];
            stag[g][quad*4+r][ 16+col] = (_Float16)wc1[r];
            stag[g][quad*4+r][ 32+col] = (_Float16)wc2[r];
            stag[g][quad*4+r][ 48+col] = (_Float16)wc3[r];
            stag[g][quad*4+r][ 64+col] = (_Float16)wc4[r];
            stag[g][quad*4+r][ 80+col] = (_Float16)wc5[r];
            stag[g][quad*4+r][ 96+col] = (_Float16)wc6[r];
            stag[g][quad*4+r][112+col] = (_Float16)wc7[r];
        }
        half8 w0h = *(const half8*)&stag[g][col][     quad*8];
        half8 w1h = *(const half8*)&stag[g][col][32 + quad*8];
        half8 w2h = *(const half8*)&stag[g][col][64 + quad*8];
        half8 w3h = *(const half8*)&stag[g][col][96 + quad*8];

        // ---- uvu: km directly in lin A-frag layout ----
        half8 fk0s0, fk0s1, fc0s0, fc0s1, fc1s0, fc1s1, fc2s0, fc2s1;
        #pragma unroll
        for (int j = 0; j < 8; ++j){
            float ww0=(float)w0h[j], ww1=(float)w1h[j];
            float ww2=(float)w2h[j], ww3=(float)w3h[j];
            float x0 = xs0[j];
            float xa = x1s[3*j], xb = x1s[3*j+1], xc = x1s[3*j+2];
            fk0s0[j] = (_Float16)(ww0 * x0 * y0);
            fk0s1[j] = (_Float16)(ww3 * (xa*y1a + xb*y1b + xc*y1c) * INV_SQRT3);
            fc0s0[j] = (_Float16)(ww1 * x0 * y1a);
            fc1s0[j] = (_Float16)(ww1 * x0 * y1b);
            fc2s0[j] = (_Float16)(ww1 * x0 * y1c);
            fc0s1[j] = (_Float16)(ww2 * xa * y0);
            fc1s1[j] = (_Float16)(ww2 * xb * y0);
            fc2s1[j] = (_Float16)(ww2 * xc * y0);
        }

        // ---- lin: k/v = km @ WL (register B-fragments) ----
        floatx4 k0a = MF16(fk0s0, rL00, zzero); k0a = MF16(fk0s1, rL01, k0a);
        floatx4 k0b = MF16(fk0s0, rL02, zzero); k0b = MF16(fk0s1, rL03, k0b);
        floatx4 kc0a = MF16(fc0s0, rL10, zzero); kc0a = MF16(fc0s1, rL11, kc0a);
        floatx4 kc0b = MF16(fc0s0, rL12, zzero); kc0b = MF16(fc0s1, rL13, kc0b);
        floatx4 kc1a = MF16(fc1s0, rL10, zzero); kc1a = MF16(fc1s1, rL11, kc1a);
        floatx4 kc1b = MF16(fc1s0, rL12, zzero); kc1b = MF16(fc1s1, rL13, kc1b);
        floatx4 kc2a = MF16(fc2s0, rL10, zzero); kc2a = MF16(fc2s1, rL11, kc2a);
        floatx4 kc2b = MF16(fc2s0, rL12, zzero); kc2b = MF16(fc2s1, rL13, kc2b);

        if (PASS == 1){
            #pragma unroll
            for (int r = 0; r < 4; ++r){
                float dd = k0a[r]*qa.x + k0b[r]*qa.y + kc0a[r]*qa.z + kc1a[r]*qa.w
                         + kc2a[r]*qb.x + kc0b[r]*qb.y + kc1b[r]*qb.z + kc2b[r]*qb.w;
                dd += __shfl_xor(dd, 1);
                dd += __shfl_xor(dd, 2);
                dd += __shfl_xor(dd, 4);
                dd += __shfl_xor(dd, 8);
                // cutoff const: diff = pos[src]-pos[src] == 0 (reference bug)
                bool valid = (tb + quad*4 + r) < dcount;
                float ev = valid ? (0.9048374180359595f * __expf(dd)) : 0.f;
                zacc += ev;
                if (col == 0 && valid)
                    cfbuf[r0 + tb + quad*4 + r] = sqrtf(ev);
            }
        } else {
            float coef0, coef1, coef2, coef3;
            #pragma unroll
            for (int r = 0; r < 4; ++r){
                int sl = tb + quad*4 + r;
                float cf = (sl < dcount) ? cfbuf[r0 + sl] : 0.f;
                if (r==0) coef0 = cf; else if (r==1) coef1 = cf;
                else if (r==2) coef2 = cf; else coef3 = cf;
            }
            macc0 += coef0*k0a[0] + coef1*k0a[1] + coef2*k0a[2] + coef3*k0a[3];
            macc1 += coef0*k0b[0] + coef1*k0b[1] + coef2*k0b[2] + coef3*k0b[3];
            macc2 += coef0*kc0a[0] + coef1*kc0a[1] + coef2*kc0a[2] + coef3*kc0a[3];
            macc3 += coef0*kc1a[0] + coef1*kc1a[1] + coef2*kc1a[2] + coef3*kc1a[3];
            macc4 += coef0*kc2a[0] + coef1*kc2a[1] + coef2*kc2a[2] + coef3*kc2a[3];
            macc5 += coef0*kc0b[0] + coef1*kc0b[1] + coef2*kc0b[2] + coef3*kc0b[3];
            macc6 += coef0*kc1b[0] + coef1*kc1b[1] + coef2*kc1b[2] + coef3*kc1b[3];
            macc7 += coef0*kc2b[0] + coef1*kc2b[1] + coef2*kc2b[2] + coef3*kc2b[3];
        }
    }

    if (PASS == 1){
        float z = zacc;
        z += __shfl_xor(z, 16); z += __shfl_xor(z, 32);
        if (lane == 0) zbuf[n] = z;
    } else {
        macc0 += __shfl_xor(macc0, 16); macc0 += __shfl_xor(macc0, 32);
        macc1 += __shfl_xor(macc1, 16); macc1 += __shfl_xor(macc1, 32);
        macc2 += __shfl_xor(macc2, 16); macc2 += __shfl_xor(macc2, 32);
        macc3 += __shfl_xor(macc3, 16); macc3 += __shfl_xor(macc3, 32);
        macc4 += __shfl_xor(macc4, 16); macc4 += __shfl_xor(macc4, 32);
        macc5 += __shfl_xor(macc5, 16); macc5 += __shfl_xor(macc5, 32);
        macc6 += __shfl_xor(macc6, 16); macc6 += __shfl_xor(macc6, 32);
        macc7 += __shfl_xor(macc7, 16); macc7 += __shfl_xor(macc7, 32);
        if (lane < 16){
            float* op = out + (size_t)n*128;
            op[col]                 += macc0 * rz;
            op[col + 16]            += macc1 * rz;
            op[32 + 3*col + 0]      += macc2 * rz;
            op[32 + 3*col + 1]      += macc3 * rz;
            op[32 + 3*col + 2]      += macc4 * rz;
            op[32 + 3*(col+16) + 0] += macc5 * rz;
            op[32 + 3*(col+16) + 1] += macc6 * rz;
            op[32 + 3*(col+16) + 2] += macc7 * rz;
        }
    }
}

extern "C" void kernel_launch(void* const* d_in, const int* in_sizes, int n_in,
                              void* d_out, int out_size, void* d_ws, size_t ws_size,
                              hipStream_t stream)
{
    const float* feats = (const float*)d_in[0];
    const float* attrs = (const float*)d_in[1];
    const float* emb   = (const float*)d_in[2];
    const float* eattr = (const float*)d_in[3];
    // d_in[4] positions: unused (reference computes positions[src]-positions[src] == 0)
    const float* Wq0  = (const float*)d_in[5];
    const float* Wq1  = (const float*)d_in[6];
    const float* Wk1  = (const float*)d_in[7];
    const float* Wk2  = (const float*)d_in[8];
    const float* Wv1  = (const float*)d_in[9];
    const float* Wv2  = (const float*)d_in[10];
    const float* Wlk0 = (const float*)d_in[11];
    const float* Wlk1 = (const float*)d_in[12];
    const float* Wlv0 = (const float*)d_in[13];
    const float* Wlv1 = (const float*)d_in[14];
    const float* Wd0  = (const float*)d_in[15];
    const float* Wd1  = (const float*)d_in[16];
    const float* Ws0  = (const float*)d_in[17];
    const float* Ws1  = (const float*)d_in[18];
    const int*   eidx = (const int*)d_in[19];

    float* out   = (float*)d_out;
    float* qdbuf = (float*)d_ws;                        // N*128 (permuted qd)
    int*   degb  = (int*)(qdbuf + (size_t)N_NODES*128); // N
    int*   rowst = degb + N_NODES;                      // N+1
    int*   curs  = rowst + N_NODES + 1;                 // N
    int*   perm  = curs + N_NODES;                      // E
    float* cfbuf = (float*)(perm + N_EDGES);            // E
    float* zbuf  = cfbuf + N_EDGES;                     // N
    _Float16* feats16 = (_Float16*)(zbuf + N_NODES);    // N*128 halves
    _Float16* emb16   = feats16 + (size_t)N_NODES*128;  // E*16 halves
    _Float16* eattr16 = emb16 + (size_t)N_EDGES*16;     // E*4 halves

    hipMemsetAsync(degb, 0, N_NODES*sizeof(int), stream);
    node_kernel<<<N_NODES/4, 256, 0, stream>>>(feats, attrs, Wq0, Wq1, Wd0, Wd1,
                                               Ws0, Ws1, qdbuf, out);
    convert_kernel<<<6144, 256, 0, stream>>>(feats, emb, eattr,
                                             feats16, emb16, eattr16);
    count_kernel<<<N_EDGES/256, 256, 0, stream>>>(eidx, degb);
    scan_kernel<<<1, 256, 0, stream>>>(degb, rowst, curs);
    scatter_kernel<<<N_EDGES/256, 256, 0, stream>>>(eidx, curs, perm);
    edge_pass<1><<<N_NODES/4, 256, 0, stream>>>(feats16, emb16, eattr16, eidx,
                                                Wk1, Wk2, Wlk0, Wlk1,
                                                qdbuf, rowst, perm,
                                                cfbuf, zbuf, out);
    edge_pass<2><<<N_NODES/4, 256, 0, stream>>>(feats16, emb16, eattr16, eidx,
                                                Wv1, Wv2, Wlv0, Wlv1,
                                                qdbuf, rowst, perm,
                                                cfbuf, zbuf, out);
}

// Round 13
// 338.273 us; speedup vs baseline: 1.2433x; 1.2433x over previous
//
#include <hip/hip_runtime.h>
#include <math.h>

#define N_NODES 8192
#define N_EDGES 262144
#define INV_SQRT3 0.5773502691896258f

typedef __attribute__((ext_vector_type(8))) _Float16 half8;
typedef __attribute__((ext_vector_type(4))) _Float16 half4;
typedef __attribute__((ext_vector_type(4))) float floatx4;

#define MF16(a,b,c) __builtin_amdgcn_mfma_f32_16x16x32_f16(a,b,c,0,0,0)

__device__ __forceinline__ float sspf(float x){
    // softplus(x) - ln2 via hw v_exp/v_log
    return (x > 20.0f) ? (x - 0.69314718f)
                       : (__logf(1.0f + __expf(x)) - 0.69314718f);
}

// ---------------------------------------------------------------------------
// Node kernel (factored sc einsum): sc = einsum('nu,nuv->nv', s, T),
// T[n,u,v] = einsum('na,uav->nuv', attrs, Ws). 4 nodes/block.
// Also computes q, qd (= Wd^T q, scales folded), stored PERMUTED:
// qdbuf[n][col*8+slot], slot = {qd0[c], qd0[c+16], qd1[3c..+2], qd1[3(c+16)..+2]}.
// ---------------------------------------------------------------------------
__global__ __launch_bounds__(256) void node_kernel(
    const float* __restrict__ feats, const float* __restrict__ attrs,
    const float* __restrict__ Wq0, const float* __restrict__ Wq1,
    const float* __restrict__ Wd0, const float* __restrict__ Wd1,
    const float* __restrict__ Ws0, const float* __restrict__ Ws1,
    float* __restrict__ qdbuf, float* __restrict__ out)
{
    __shared__ float sa[4][16];
    __shared__ float sT[4][4][32];
    __shared__ float Tl[2][4][1152];   // T, rows stride 36
    __shared__ float qT[4][4][32];
    __shared__ float qsh[4][128];

    const int t  = threadIdx.x;
    const int nb = blockIdx.x * 4;

    const float inv_sqrt32 = 0.17677669529663687f;
    const float sc_scale   = 0.04419417382415922f;
    const float d_scale    = 0.022097086912079608f;

    for (int i = t; i < 512; i += 256){
        int nn = i >> 7, r = i & 127;
        int p = r >> 5, u = r & 31;
        sT[nn][p][u] = feats[(size_t)(nb+nn)*128 + ((p==0) ? u : 32 + u*3 + (p-1))];
    }
    if (t < 64) sa[t>>4][t&15] = attrs[(size_t)(nb + (t>>4))*16 + (t&15)];
    __syncthreads();

    const int v  = t & 31;
    const int g5 = (t >> 5) & 3;
    const int hi = t >> 7;

    {
        const float* __restrict__ Wm = hi ? Ws1 : Ws0;
        float sar[4][16];
        #pragma unroll
        for (int nn = 0; nn < 4; ++nn)
            #pragma unroll
            for (int a = 0; a < 16; ++a) sar[nn][a] = sa[nn][a];
        #pragma unroll
        for (int uu = 0; uu < 8; ++uu){
            int u = g5*8 + uu;
            float a0=0.f, a1=0.f, a2=0.f, a3=0.f;
            #pragma unroll
            for (int a = 0; a < 16; ++a){
                float w = Wm[(u*16 + a)*32 + v];
                a0 += sar[0][a]*w; a1 += sar[1][a]*w;
                a2 += sar[2][a]*w; a3 += sar[3][a]*w;
            }
            Tl[hi][0][v*36+u] = a0; Tl[hi][1][v*36+u] = a1;
            Tl[hi][2][v*36+u] = a2; Tl[hi][3][v*36+u] = a3;
        }
    }
    __syncthreads();

    const int p  = g5;
    const int n0 = hi*2, n1 = n0 + 1;
    const int mm = (p==0) ? 0 : 1;
    const float* __restrict__ Wqp = (p==0) ? Wq0 : Wq1;
    const float* __restrict__ Wdp = (p==0) ? Wd0 : Wd1;
    const int oidx = (p==0) ? v : 32 + v*3 + (p-1);

    float c0=0.f, c1=0.f;
    #pragma unroll
    for (int uc = 0; uc < 8; ++uc){
        float4 t0 = *(const float4*)&Tl[mm][n0][v*36 + uc*4];
        float4 t1 = *(const float4*)&Tl[mm][n1][v*36 + uc*4];
        float4 s0 = *(const float4*)&sT[n0][p][uc*4];
        float4 s1 = *(const float4*)&sT[n1][p][uc*4];
        c0 += t0.x*s0.x + t0.y*s0.y + t0.z*s0.z + t0.w*s0.w;
        c1 += t1.x*s1.x + t1.y*s1.y + t1.z*s1.z + t1.w*s1.w;
    }
    out[(size_t)(nb+n0)*128 + oidx] = c0 * sc_scale;
    out[(size_t)(nb+n1)*128 + oidx] = c1 * sc_scale;

    float q0=0.f, q1=0.f;
    #pragma unroll
    for (int u = 0; u < 32; ++u){
        float w = Wqp[u*32 + v];
        q0 += sT[n0][p][u] * w;
        q1 += sT[n1][p][u] * w;
    }
    qT[n0][p][v] = q0 * inv_sqrt32;
    qT[n1][p][v] = q1 * inv_sqrt32;
    __syncthreads();

    float d0=0.f, d1=0.f;
    #pragma unroll
    for (int u = 0; u < 32; ++u){
        float w = Wdp[u*32 + v];
        d0 += qT[n0][p][u] * w;
        d1 += qT[n1][p][u] * w;
    }
    float dsc = (p==0) ? d_scale : d_scale * INV_SQRT3;
    qsh[n0][oidx] = d0 * dsc;
    qsh[n1][oidx] = d1 * dsc;
    __syncthreads();

    for (int i = t; i < 512; i += 256){
        int nn = i >> 7, tt = i & 127;
        int col = tt >> 3, slot = tt & 7;
        int src;
        if      (slot == 0) src = col;
        else if (slot == 1) src = col + 16;
        else if (slot <  5) src = 32 + 3*col + (slot-2);
        else                src = 32 + 3*(col+16) + (slot-5);
        qdbuf[(size_t)(nb+nn)*128 + tt] = qsh[nn][src];
    }
}

// ---------------------------------------------------------------------------
// fp16 conversion of gathered streams: feats (1M fl), emb (4M), eattr (1M).
// ---------------------------------------------------------------------------
__global__ __launch_bounds__(256) void convert_kernel(
    const float* __restrict__ feats, const float* __restrict__ emb,
    const float* __restrict__ eattr,
    _Float16* __restrict__ feats16, _Float16* __restrict__ emb16,
    _Float16* __restrict__ eattr16)
{
    int idx = blockIdx.x*256 + threadIdx.x;
    const float* src; _Float16* dst; int off;
    if (idx < 262144)            { src = feats; dst = feats16; off = idx; }
    else if (idx < 1310720)      { src = emb;   dst = emb16;   off = idx - 262144; }
    else                         { src = eattr; dst = eattr16; off = idx - 1310720; }
    float4 v = *(const float4*)(src + (size_t)off*4);
    half4 h;
    h[0]=(_Float16)v.x; h[1]=(_Float16)v.y; h[2]=(_Float16)v.z; h[3]=(_Float16)v.w;
    *(half4*)(dst + (size_t)off*4) = h;
}

// ---------------------------------------------------------------------------
// CSR build: histogram by dst -> exclusive scan -> scatter permutation.
// ---------------------------------------------------------------------------
__global__ __launch_bounds__(256) void count_kernel(
    const int* __restrict__ eidx, int* __restrict__ degb)
{
    int e = blockIdx.x*256 + threadIdx.x;
    atomicAdd(&degb[eidx[N_EDGES + e]], 1);
}

__global__ __launch_bounds__(256) void scan_kernel(
    const int* __restrict__ degb, int* __restrict__ rowstart,
    int* __restrict__ cursor)
{
    __shared__ int part[256];
    int t = threadIdx.x;
    int loc[32];
    int s = 0;
    #pragma unroll
    for (int i = 0; i < 32; ++i){ loc[i] = s; s += degb[t*32 + i]; }
    part[t] = s;
    __syncthreads();
    for (int d = 1; d < 256; d <<= 1){
        int v = (t >= d) ? part[t-d] : 0;
        __syncthreads();
        part[t] += v;
        __syncthreads();
    }
    int excl = part[t] - s;
    #pragma unroll
    for (int i = 0; i < 32; ++i){
        int v = excl + loc[i];
        rowstart[t*32 + i] = v;
        cursor[t*32 + i]   = v;
    }
    if (t == 255) rowstart[N_NODES] = excl + s;
}

__global__ __launch_bounds__(256) void scatter_kernel(
    const int* __restrict__ eidx, int* __restrict__ cursor,
    int* __restrict__ perm)
{
    int e = blockIdx.x*256 + threadIdx.x;
    int p = atomicAdd(&cursor[eidx[N_EDGES + e]], 1);
    perm[p] = e;
}

// ---------------------------------------------------------------------------
// Node-centric MFMA edge pass. fp16 gathered inputs (halve the L2-miss
// gather traffic) on the R11-proven structure: ALL weight fragments in LDS
// (fW1 4K + fW2 16K + fL0 4K + fL1 4K + stag 17408 = 46080 B -> 3 blocks/CU),
// launch_bounds(256,3) (R11: VGPR 84, zero scratch). R12 post-mortem: register
// B-frags + (256,4) forced VGPR 64 -> full spill (FETCH 271 MB, WRITE 165 MB).
// NO atomics.
// mfma_f32_16x16x32_f16 layouts (measured, learn_hip m89/m120):
// A[m=lane&15][k=quad*8+j]; B[k=quad*8+j][n=lane&15]; C col=lane&15,
// row=quad*4+reg.
// ---------------------------------------------------------------------------
template<int PASS>
__global__ __launch_bounds__(256, 3) void edge_pass(
    const _Float16* __restrict__ feats16, const _Float16* __restrict__ emb16,
    const _Float16* __restrict__ eattr16, const int* __restrict__ eidx,
    const float* __restrict__ W1,  const float* __restrict__ W2,
    const float* __restrict__ WL0, const float* __restrict__ WL1,
    const float* __restrict__ qdbuf,
    const int* __restrict__ rowstart, const int* __restrict__ perm,
    float* __restrict__ cfbuf, float* __restrict__ zbuf,
    float* __restrict__ out)
{
    __shared__ half8 fW1[4][64];
    __shared__ half8 fW2[16][64];
    __shared__ half8 fL0[4][64];
    __shared__ half8 fL1[4][64];
    __shared__ _Float16 stag[4][16][136];

    const int t    = threadIdx.x;
    const int lane = t & 63;
    const int col  = lane & 15;
    const int quad = lane >> 4;
    const int g    = t >> 6;

    // ---- preload weight fragments (scales folded) ----
    {
        half8 f;
        #pragma unroll
        for (int j = 0; j < 8; ++j){
            int k = quad*8 + j;
            f[j] = (k < 16) ? (_Float16)(W1[k*64 + g*16 + col] * 0.25f) : (_Float16)0.f;
        }
        fW1[g][lane] = f;
    }
    #pragma unroll
    for (int ff = 0; ff < 4; ++ff){
        int fr = g*4 + ff, tile = fr >> 1, s = fr & 1;
        half8 f;
        #pragma unroll
        for (int j = 0; j < 8; ++j)
            f[j] = (_Float16)(W2[(s*32 + quad*8 + j)*128 + tile*16 + col] * 0.125f);
        fW2[fr][lane] = f;
    }
    {
        int tile = g >> 1, s = g & 1;
        half8 f0, f1;
        #pragma unroll
        for (int j = 0; j < 8; ++j){
            int k = (s*32 + quad*8 + j)*32 + tile*16 + col;
            f0[j] = (_Float16)(WL0[k] * 0.125f);
            f1[j] = (_Float16)(WL1[k] * 0.125f);
        }
        fL0[g][lane] = f0; fL1[g][lane] = f1;
    }
    __syncthreads();     // the only block-wide barrier

    const floatx4 zzero = {0.f, 0.f, 0.f, 0.f};

    const int n  = blockIdx.x*4 + g;
    const int r0 = rowstart[n];
    const int dcount = rowstart[n+1] - r0;

    float4 qa, qb;
    if (PASS == 1){
        const float* qdp = qdbuf + (size_t)n*128 + col*8;
        qa = *(const float4*)qdp;
        qb = *(const float4*)(qdp + 4);
    }
    float rz = 0.f;
    if (PASS == 2){
        float z = zbuf[n];
        rz = (z > 0.f) ? rsqrtf(z) : 0.f;
    }

    float macc0=0.f, macc1=0.f, macc2=0.f, macc3=0.f;
    float macc4=0.f, macc5=0.f, macc6=0.f, macc7=0.f;
    float zacc = 0.f;

    for (int tb = 0; tb < dcount; tb += 16){
        int slot = tb + col;
        int eA = perm[r0 + ((slot < dcount) ? slot : (dcount-1))];

        // ---- A-fragment: emb16 rows, direct half8 (K=16 padded to 32) ----
        half8 ea;
        if (quad < 2){
            ea = *(const half8*)(emb16 + (size_t)eA*16 + quad*8);
        } else {
            #pragma unroll
            for (int j = 0; j < 8; ++j) ea[j] = (_Float16)0.f;
        }

        const int srcm = eidx[eA];
        const _Float16* fsrc = feats16 + (size_t)srcm*128;
        half4 hy = *(const half4*)(eattr16 + (size_t)eA*4);
        const float y0 = (float)hy[0], y1a = (float)hy[1],
                    y1b = (float)hy[2], y1c = (float)hy[3];

        half8 hx = *(const half8*)(fsrc + quad*8);
        float xs0[8];
        #pragma unroll
        for (int j = 0; j < 8; ++j) xs0[j] = (float)hx[j];
        half8 hz0 = *(const half8*)(fsrc + 32 + quad*24);
        half8 hz1 = *(const half8*)(fsrc + 32 + quad*24 + 8);
        half8 hz2 = *(const half8*)(fsrc + 32 + quad*24 + 16);
        float x1s[24];
        #pragma unroll
        for (int j = 0; j < 8; ++j){
            x1s[j]      = (float)hz0[j];
            x1s[8 + j]  = (float)hz1[j];
            x1s[16 + j] = (float)hz2[j];
        }

        // ---- GEMM1 -> ssp -> h staging ----
        floatx4 hA = MF16(ea, fW1[0][lane], zzero);
        floatx4 hB = MF16(ea, fW1[1][lane], zzero);
        floatx4 hC = MF16(ea, fW1[2][lane], zzero);
        floatx4 hD = MF16(ea, fW1[3][lane], zzero);
        #pragma unroll
        for (int r = 0; r < 4; ++r){
            stag[g][quad*4+r][   col] = (_Float16)sspf(hA[r]);
            stag[g][quad*4+r][16+col] = (_Float16)sspf(hB[r]);
            stag[g][quad*4+r][32+col] = (_Float16)sspf(hC[r]);
            stag[g][quad*4+r][48+col] = (_Float16)sspf(hD[r]);
        }
        half8 a0 = *(const half8*)&stag[g][col][quad*8];
        half8 a1 = *(const half8*)&stag[g][col][32 + quad*8];

        // ---- GEMM2: w = h @ W2 (writes overlay h; same-wave DS in-order) ----
        floatx4 wc0 = MF16(a0, fW2[ 0][lane], zzero); wc0 = MF16(a1, fW2[ 1][lane], wc0);
        floatx4 wc1 = MF16(a0, fW2[ 2][lane], zzero); wc1 = MF16(a1, fW2[ 3][lane], wc1);
        floatx4 wc2 = MF16(a0, fW2[ 4][lane], zzero); wc2 = MF16(a1, fW2[ 5][lane], wc2);
        floatx4 wc3 = MF16(a0, fW2[ 6][lane], zzero); wc3 = MF16(a1, fW2[ 7][lane], wc3);
        floatx4 wc4 = MF16(a0, fW2[ 8][lane], zzero); wc4 = MF16(a1, fW2[ 9][lane], wc4);
        floatx4 wc5 = MF16(a0, fW2[10][lane], zzero); wc5 = MF16(a1, fW2[11][lane], wc5);
        floatx4 wc6 = MF16(a0, fW2[12][lane], zzero); wc6 = MF16(a1, fW2[13][lane], wc6);
        floatx4 wc7 = MF16(a0, fW2[14][lane], zzero); wc7 = MF16(a1, fW2[15][lane], wc7);
        #pragma unroll
        for (int r = 0; r < 4; ++r){
            stag[g][quad*4+r][  0+col] = (_Float16)wc0[r];
            stag[g][quad*4+r][ 16+col] = (_Float16)wc1[r];
            stag[g][quad*4+r][ 32+col] = (_Float16)wc2[r];
            stag[g][quad*4+r][ 48+col] = (_Float16)wc3[r];
            stag[g][quad*4+r][ 64+col] = (_Float16)wc4[r];
            stag[g][quad*4+r][ 80+col] = (_Float16)wc5[r];
            stag[g][quad*4+r][ 96+col] = (_Float16)wc6[r];
            stag[g][quad*4+r][112+col] = (_Float16)wc7[r];
        }
        half8 w0h = *(const half8*)&stag[g][col][     quad*8];
        half8 w1h = *(const half8*)&stag[g][col][32 + quad*8];
        half8 w2h = *(const half8*)&stag[g][col][64 + quad*8];
        half8 w3h = *(const half8*)&stag[g][col][96 + quad*8];

        // ---- uvu: km directly in lin A-frag layout ----
        half8 fk0s0, fk0s1, fc0s0, fc0s1, fc1s0, fc1s1, fc2s0, fc2s1;
        #pragma unroll
        for (int j = 0; j < 8; ++j){
            float ww0=(float)w0h[j], ww1=(float)w1h[j];
            float ww2=(float)w2h[j], ww3=(float)w3h[j];
            float x0 = xs0[j];
            float xa = x1s[3*j], xb = x1s[3*j+1], xc = x1s[3*j+2];
            fk0s0[j] = (_Float16)(ww0 * x0 * y0);
            fk0s1[j] = (_Float16)(ww3 * (xa*y1a + xb*y1b + xc*y1c) * INV_SQRT3);
            fc0s0[j] = (_Float16)(ww1 * x0 * y1a);
            fc1s0[j] = (_Float16)(ww1 * x0 * y1b);
            fc2s0[j] = (_Float16)(ww1 * x0 * y1c);
            fc0s1[j] = (_Float16)(ww2 * xa * y0);
            fc1s1[j] = (_Float16)(ww2 * xb * y0);
            fc2s1[j] = (_Float16)(ww2 * xc * y0);
        }

        // ---- lin: k/v = km @ WL ----
        floatx4 k0a = MF16(fk0s0, fL0[0][lane], zzero); k0a = MF16(fk0s1, fL0[1][lane], k0a);
        floatx4 k0b = MF16(fk0s0, fL0[2][lane], zzero); k0b = MF16(fk0s1, fL0[3][lane], k0b);
        floatx4 kc0a = MF16(fc0s0, fL1[0][lane], zzero); kc0a = MF16(fc0s1, fL1[1][lane], kc0a);
        floatx4 kc0b = MF16(fc0s0, fL1[2][lane], zzero); kc0b = MF16(fc0s1, fL1[3][lane], kc0b);
        floatx4 kc1a = MF16(fc1s0, fL1[0][lane], zzero); kc1a = MF16(fc1s1, fL1[1][lane], kc1a);
        floatx4 kc1b = MF16(fc1s0, fL1[2][lane], zzero); kc1b = MF16(fc1s1, fL1[3][lane], kc1b);
        floatx4 kc2a = MF16(fc2s0, fL1[0][lane], zzero); kc2a = MF16(fc2s1, fL1[1][lane], kc2a);
        floatx4 kc2b = MF16(fc2s0, fL1[2][lane], zzero); kc2b = MF16(fc2s1, fL1[3][lane], kc2b);

        if (PASS == 1){
            #pragma unroll
            for (int r = 0; r < 4; ++r){
                float dd = k0a[r]*qa.x + k0b[r]*qa.y + kc0a[r]*qa.z + kc1a[r]*qa.w
                         + kc2a[r]*qb.x + kc0b[r]*qb.y + kc1b[r]*qb.z + kc2b[r]*qb.w;
                dd += __shfl_xor(dd, 1);
                dd += __shfl_xor(dd, 2);
                dd += __shfl_xor(dd, 4);
                dd += __shfl_xor(dd, 8);
                // cutoff const: diff = pos[src]-pos[src] == 0 (reference bug)
                bool valid = (tb + quad*4 + r) < dcount;
                float ev = valid ? (0.9048374180359595f * __expf(dd)) : 0.f;
                zacc += ev;
                if (col == 0 && valid)
                    cfbuf[r0 + tb + quad*4 + r] = sqrtf(ev);
            }
        } else {
            float coef0, coef1, coef2, coef3;
            #pragma unroll
            for (int r = 0; r < 4; ++r){
                int sl = tb + quad*4 + r;
                float cf = (sl < dcount) ? cfbuf[r0 + sl] : 0.f;
                if (r==0) coef0 = cf; else if (r==1) coef1 = cf;
                else if (r==2) coef2 = cf; else coef3 = cf;
            }
            macc0 += coef0*k0a[0] + coef1*k0a[1] + coef2*k0a[2] + coef3*k0a[3];
            macc1 += coef0*k0b[0] + coef1*k0b[1] + coef2*k0b[2] + coef3*k0b[3];
            macc2 += coef0*kc0a[0] + coef1*kc0a[1] + coef2*kc0a[2] + coef3*kc0a[3];
            macc3 += coef0*kc1a[0] + coef1*kc1a[1] + coef2*kc1a[2] + coef3*kc1a[3];
            macc4 += coef0*kc2a[0] + coef1*kc2a[1] + coef2*kc2a[2] + coef3*kc2a[3];
            macc5 += coef0*kc0b[0] + coef1*kc0b[1] + coef2*kc0b[2] + coef3*kc0b[3];
            macc6 += coef0*kc1b[0] + coef1*kc1b[1] + coef2*kc1b[2] + coef3*kc1b[3];
            macc7 += coef0*kc2b[0] + coef1*kc2b[1] + coef2*kc2b[2] + coef3*kc2b[3];
        }
    }

    if (PASS == 1){
        float z = zacc;
        z += __shfl_xor(z, 16); z += __shfl_xor(z, 32);
        if (lane == 0) zbuf[n] = z;
    } else {
        macc0 += __shfl_xor(macc0, 16); macc0 += __shfl_xor(macc0, 32);
        macc1 += __shfl_xor(macc1, 16); macc1 += __shfl_xor(macc1, 32);
        macc2 += __shfl_xor(macc2, 16); macc2 += __shfl_xor(macc2, 32);
        macc3 += __shfl_xor(macc3, 16); macc3 += __shfl_xor(macc3, 32);
        macc4 += __shfl_xor(macc4, 16); macc4 += __shfl_xor(macc4, 32);
        macc5 += __shfl_xor(macc5, 16); macc5 += __shfl_xor(macc5, 32);
        macc6 += __shfl_xor(macc6, 16); macc6 += __shfl_xor(macc6, 32);
        macc7 += __shfl_xor(macc7, 16); macc7 += __shfl_xor(macc7, 32);
        if (lane < 16){
            float* op = out + (size_t)n*128;
            op[col]                 += macc0 * rz;
            op[col + 16]            += macc1 * rz;
            op[32 + 3*col + 0]      += macc2 * rz;
            op[32 + 3*col + 1]      += macc3 * rz;
            op[32 + 3*col + 2]      += macc4 * rz;
            op[32 + 3*(col+16) + 0] += macc5 * rz;
            op[32 + 3*(col+16) + 1] += macc6 * rz;
            op[32 + 3*(col+16) + 2] += macc7 * rz;
        }
    }
}

extern "C" void kernel_launch(void* const* d_in, const int* in_sizes, int n_in,
                              void* d_out, int out_size, void* d_ws, size_t ws_size,
                              hipStream_t stream)
{
    const float* feats = (const float*)d_in[0];
    const float* attrs = (const float*)d_in[1];
    const float* emb   = (const float*)d_in[2];
    const float* eattr = (const float*)d_in[3];
    // d_in[4] positions: unused (reference computes positions[src]-positions[src] == 0)
    const float* Wq0  = (const float*)d_in[5];
    const float* Wq1  = (const float*)d_in[6];
    const float* Wk1  = (const float*)d_in[7];
    const float* Wk2  = (const float*)d_in[8];
    const float* Wv1  = (const float*)d_in[9];
    const float* Wv2  = (const float*)d_in[10];
    const float* Wlk0 = (const float*)d_in[11];
    const float* Wlk1 = (const float*)d_in[12];
    const float* Wlv0 = (const float*)d_in[13];
    const float* Wlv1 = (const float*)d_in[14];
    const float* Wd0  = (const float*)d_in[15];
    const float* Wd1  = (const float*)d_in[16];
    const float* Ws0  = (const float*)d_in[17];
    const float* Ws1  = (const float*)d_in[18];
    const int*   eidx = (const int*)d_in[19];

    float* out   = (float*)d_out;
    float* qdbuf = (float*)d_ws;                        // N*128 (permuted qd)
    int*   degb  = (int*)(qdbuf + (size_t)N_NODES*128); // N
    int*   rowst = degb + N_NODES;                      // N+1
    int*   curs  = rowst + N_NODES + 1;                 // N
    int*   perm  = curs + N_NODES;                      // E
    float* cfbuf = (float*)(perm + N_EDGES);            // E
    float* zbuf  = cfbuf + N_EDGES;                     // N
    _Float16* feats16 = (_Float16*)(zbuf + N_NODES);    // N*128 halves
    _Float16* emb16   = feats16 + (size_t)N_NODES*128;  // E*16 halves
    _Float16* eattr16 = emb16 + (size_t)N_EDGES*16;     // E*4 halves

    hipMemsetAsync(degb, 0, N_NODES*sizeof(int), stream);
    node_kernel<<<N_NODES/4, 256, 0, stream>>>(feats, attrs, Wq0, Wq1, Wd0, Wd1,
                                               Ws0, Ws1, qdbuf, out);
    convert_kernel<<<6144, 256, 0, stream>>>(feats, emb, eattr,
                                             feats16, emb16, eattr16);
    count_kernel<<<N_EDGES/256, 256, 0, stream>>>(eidx, degb);
    scan_kernel<<<1, 256, 0, stream>>>(degb, rowst, curs);
    scatter_kernel<<<N_EDGES/256, 256, 0, stream>>>(eidx, curs, perm);
    edge_pass<1><<<N_NODES/4, 256, 0, stream>>>(feats16, emb16, eattr16, eidx,
                                                Wk1, Wk2, Wlk0, Wlk1,
                                                qdbuf, rowst, perm,
                                                cfbuf, zbuf, out);
    edge_pass<2><<<N_NODES/4, 256, 0, stream>>>(feats16, emb16, eattr16, eidx,
                                                Wv1, Wv2, Wlv0, Wlv1,
                                                qdbuf, rowst, perm,
                                                cfbuf, zbuf, out);
}

// Round 14
// 320.018 us; speedup vs baseline: 1.3142x; 1.0570x over previous
//
#include <hip/hip_runtime.h>
#include <math.h>

#define N_NODES 8192
#define N_EDGES 262144
#define INV_SQRT3 0.5773502691896258f

typedef __attribute__((ext_vector_type(8))) _Float16 half8;
typedef __attribute__((ext_vector_type(4))) _Float16 half4;
typedef __attribute__((ext_vector_type(4))) float floatx4;

#define MF16(a,b,c) __builtin_amdgcn_mfma_f32_16x16x32_f16(a,b,c,0,0,0)

__device__ __forceinline__ float sspf(float x){
    // softplus(x) - ln2 via hw v_exp/v_log
    return (x > 20.0f) ? (x - 0.69314718f)
                       : (__logf(1.0f + __expf(x)) - 0.69314718f);
}

// ---------------------------------------------------------------------------
// Node kernel (factored sc einsum): sc = einsum('nu,nuv->nv', s, T),
// T[n,u,v] = einsum('na,uav->nuv', attrs, Ws). 4 nodes/block.
// Also computes q, qd (= Wd^T q, scales folded), stored PERMUTED:
// qdbuf[n][col*8+slot], slot = {qd0[c], qd0[c+16], qd1[3c..+2], qd1[3(c+16)..+2]}.
// ---------------------------------------------------------------------------
__global__ __launch_bounds__(256) void node_kernel(
    const float* __restrict__ feats, const float* __restrict__ attrs,
    const float* __restrict__ Wq0, const float* __restrict__ Wq1,
    const float* __restrict__ Wd0, const float* __restrict__ Wd1,
    const float* __restrict__ Ws0, const float* __restrict__ Ws1,
    float* __restrict__ qdbuf, float* __restrict__ out)
{
    __shared__ float sa[4][16];
    __shared__ float sT[4][4][32];
    __shared__ float Tl[2][4][1152];   // T, rows stride 36
    __shared__ float qT[4][4][32];
    __shared__ float qsh[4][128];

    const int t  = threadIdx.x;
    const int nb = blockIdx.x * 4;

    const float inv_sqrt32 = 0.17677669529663687f;
    const float sc_scale   = 0.04419417382415922f;
    const float d_scale    = 0.022097086912079608f;

    for (int i = t; i < 512; i += 256){
        int nn = i >> 7, r = i & 127;
        int p = r >> 5, u = r & 31;
        sT[nn][p][u] = feats[(size_t)(nb+nn)*128 + ((p==0) ? u : 32 + u*3 + (p-1))];
    }
    if (t < 64) sa[t>>4][t&15] = attrs[(size_t)(nb + (t>>4))*16 + (t&15)];
    __syncthreads();

    const int v  = t & 31;
    const int g5 = (t >> 5) & 3;
    const int hi = t >> 7;

    {
        const float* __restrict__ Wm = hi ? Ws1 : Ws0;
        float sar[4][16];
        #pragma unroll
        for (int nn = 0; nn < 4; ++nn)
            #pragma unroll
            for (int a = 0; a < 16; ++a) sar[nn][a] = sa[nn][a];
        #pragma unroll
        for (int uu = 0; uu < 8; ++uu){
            int u = g5*8 + uu;
            float a0=0.f, a1=0.f, a2=0.f, a3=0.f;
            #pragma unroll
            for (int a = 0; a < 16; ++a){
                float w = Wm[(u*16 + a)*32 + v];
                a0 += sar[0][a]*w; a1 += sar[1][a]*w;
                a2 += sar[2][a]*w; a3 += sar[3][a]*w;
            }
            Tl[hi][0][v*36+u] = a0; Tl[hi][1][v*36+u] = a1;
            Tl[hi][2][v*36+u] = a2; Tl[hi][3][v*36+u] = a3;
        }
    }
    __syncthreads();

    const int p  = g5;
    const int n0 = hi*2, n1 = n0 + 1;
    const int mm = (p==0) ? 0 : 1;
    const float* __restrict__ Wqp = (p==0) ? Wq0 : Wq1;
    const float* __restrict__ Wdp = (p==0) ? Wd0 : Wd1;
    const int oidx = (p==0) ? v : 32 + v*3 + (p-1);

    float c0=0.f, c1=0.f;
    #pragma unroll
    for (int uc = 0; uc < 8; ++uc){
        float4 t0 = *(const float4*)&Tl[mm][n0][v*36 + uc*4];
        float4 t1 = *(const float4*)&Tl[mm][n1][v*36 + uc*4];
        float4 s0 = *(const float4*)&sT[n0][p][uc*4];
        float4 s1 = *(const float4*)&sT[n1][p][uc*4];
        c0 += t0.x*s0.x + t0.y*s0.y + t0.z*s0.z + t0.w*s0.w;
        c1 += t1.x*s1.x + t1.y*s1.y + t1.z*s1.z + t1.w*s1.w;
    }
    out[(size_t)(nb+n0)*128 + oidx] = c0 * sc_scale;
    out[(size_t)(nb+n1)*128 + oidx] = c1 * sc_scale;

    float q0=0.f, q1=0.f;
    #pragma unroll
    for (int u = 0; u < 32; ++u){
        float w = Wqp[u*32 + v];
        q0 += sT[n0][p][u] * w;
        q1 += sT[n1][p][u] * w;
    }
    qT[n0][p][v] = q0 * inv_sqrt32;
    qT[n1][p][v] = q1 * inv_sqrt32;
    __syncthreads();

    float d0=0.f, d1=0.f;
    #pragma unroll
    for (int u = 0; u < 32; ++u){
        float w = Wdp[u*32 + v];
        d0 += qT[n0][p][u] * w;
        d1 += qT[n1][p][u] * w;
    }
    float dsc = (p==0) ? d_scale : d_scale * INV_SQRT3;
    qsh[n0][oidx] = d0 * dsc;
    qsh[n1][oidx] = d1 * dsc;
    __syncthreads();

    for (int i = t; i < 512; i += 256){
        int nn = i >> 7, tt = i & 127;
        int col = tt >> 3, slot = tt & 7;
        int src;
        if      (slot == 0) src = col;
        else if (slot == 1) src = col + 16;
        else if (slot <  5) src = 32 + 3*col + (slot-2);
        else                src = 32 + 3*(col+16) + (slot-5);
        qdbuf[(size_t)(nb+nn)*128 + tt] = qsh[nn][src];
    }
}

// ---------------------------------------------------------------------------
// fp16 conversion of feats only (node-indexed gather target in edge pass).
// 262144 float4s -> 1024 blocks.
// ---------------------------------------------------------------------------
__global__ __launch_bounds__(256) void convert_kernel(
    const float* __restrict__ feats, _Float16* __restrict__ feats16)
{
    int idx = blockIdx.x*256 + threadIdx.x;
    float4 v = *(const float4*)(feats + (size_t)idx*4);
    half4 h;
    h[0]=(_Float16)v.x; h[1]=(_Float16)v.y; h[2]=(_Float16)v.z; h[3]=(_Float16)v.w;
    *(half4*)(feats16 + (size_t)idx*4) = h;
}

// ---------------------------------------------------------------------------
// CSR build: histogram by dst -> exclusive scan -> scatter+REORDER.
// scatter writes the per-edge streams in CSR position order so the edge
// passes read them SEQUENTIALLY (R13 post-mortem: random emb/eattr/eidx
// line over-fetch ~48 MB/pass + 3-deep gather chain).
// ---------------------------------------------------------------------------
__global__ __launch_bounds__(256) void count_kernel(
    const int* __restrict__ eidx, int* __restrict__ degb)
{
    int e = blockIdx.x*256 + threadIdx.x;
    atomicAdd(&degb[eidx[N_EDGES + e]], 1);
}

__global__ __launch_bounds__(256) void scan_kernel(
    const int* __restrict__ degb, int* __restrict__ rowstart,
    int* __restrict__ cursor)
{
    __shared__ int part[256];
    int t = threadIdx.x;
    int loc[32];
    int s = 0;
    #pragma unroll
    for (int i = 0; i < 32; ++i){ loc[i] = s; s += degb[t*32 + i]; }
    part[t] = s;
    __syncthreads();
    for (int d = 1; d < 256; d <<= 1){
        int v = (t >= d) ? part[t-d] : 0;
        __syncthreads();
        part[t] += v;
        __syncthreads();
    }
    int excl = part[t] - s;
    #pragma unroll
    for (int i = 0; i < 32; ++i){
        int v = excl + loc[i];
        rowstart[t*32 + i] = v;
        cursor[t*32 + i]   = v;
    }
    if (t == 255) rowstart[N_NODES] = excl + s;
}

__global__ __launch_bounds__(256) void scatter_kernel(
    const int* __restrict__ eidx, const float* __restrict__ emb,
    const float* __restrict__ eattr, int* __restrict__ cursor,
    int* __restrict__ srcp, _Float16* __restrict__ emb16p,
    float* __restrict__ eattrp)
{
    int e = blockIdx.x*256 + threadIdx.x;
    int p = atomicAdd(&cursor[eidx[N_EDGES + e]], 1);
    srcp[p] = eidx[e];
    *(float4*)(eattrp + (size_t)p*4) = *(const float4*)(eattr + (size_t)e*4);
    const float4* ep = (const float4*)(emb + (size_t)e*16);
    float4 v0 = ep[0], v1 = ep[1], v2 = ep[2], v3 = ep[3];
    half8 h0, h1;
    h0[0]=(_Float16)v0.x; h0[1]=(_Float16)v0.y; h0[2]=(_Float16)v0.z; h0[3]=(_Float16)v0.w;
    h0[4]=(_Float16)v1.x; h0[5]=(_Float16)v1.y; h0[6]=(_Float16)v1.z; h0[7]=(_Float16)v1.w;
    h1[0]=(_Float16)v2.x; h1[1]=(_Float16)v2.y; h1[2]=(_Float16)v2.z; h1[3]=(_Float16)v2.w;
    h1[4]=(_Float16)v3.x; h1[5]=(_Float16)v3.y; h1[6]=(_Float16)v3.z; h1[7]=(_Float16)v3.w;
    *(half8*)(emb16p + (size_t)p*16)     = h0;
    *(half8*)(emb16p + (size_t)p*16 + 8) = h1;
}

// ---------------------------------------------------------------------------
// Node-centric MFMA edge pass. All per-edge streams (srcp/emb16p/eattrp)
// are CSR-ordered -> sequential, line-exact reads, no perm indirection.
// feats16 is the only remaining gather (256 B/edge by src). Weights all in
// LDS (46080 B -> 3 blocks/CU), launch_bounds(256,3) (VGPR 84, no scratch).
// NO atomics.
// mfma_f32_16x16x32_f16 layouts (measured, learn_hip m89/m120):
// A[m=lane&15][k=quad*8+j]; B[k=quad*8+j][n=lane&15]; C col=lane&15,
// row=quad*4+reg.
// ---------------------------------------------------------------------------
template<int PASS>
__global__ __launch_bounds__(256, 3) void edge_pass(
    const _Float16* __restrict__ feats16, const _Float16* __restrict__ emb16p,
    const float* __restrict__ eattrp, const int* __restrict__ srcp,
    const float* __restrict__ W1,  const float* __restrict__ W2,
    const float* __restrict__ WL0, const float* __restrict__ WL1,
    const float* __restrict__ qdbuf,
    const int* __restrict__ rowstart,
    float* __restrict__ cfbuf, float* __restrict__ zbuf,
    float* __restrict__ out)
{
    __shared__ half8 fW1[4][64];
    __shared__ half8 fW2[16][64];
    __shared__ half8 fL0[4][64];
    __shared__ half8 fL1[4][64];
    __shared__ _Float16 stag[4][16][136];

    const int t    = threadIdx.x;
    const int lane = t & 63;
    const int col  = lane & 15;
    const int quad = lane >> 4;
    const int g    = t >> 6;

    // ---- preload weight fragments (scales folded) ----
    {
        half8 f;
        #pragma unroll
        for (int j = 0; j < 8; ++j){
            int k = quad*8 + j;
            f[j] = (k < 16) ? (_Float16)(W1[k*64 + g*16 + col] * 0.25f) : (_Float16)0.f;
        }
        fW1[g][lane] = f;
    }
    #pragma unroll
    for (int ff = 0; ff < 4; ++ff){
        int fr = g*4 + ff, tile = fr >> 1, s = fr & 1;
        half8 f;
        #pragma unroll
        for (int j = 0; j < 8; ++j)
            f[j] = (_Float16)(W2[(s*32 + quad*8 + j)*128 + tile*16 + col] * 0.125f);
        fW2[fr][lane] = f;
    }
    {
        int tile = g >> 1, s = g & 1;
        half8 f0, f1;
        #pragma unroll
        for (int j = 0; j < 8; ++j){
            int k = (s*32 + quad*8 + j)*32 + tile*16 + col;
            f0[j] = (_Float16)(WL0[k] * 0.125f);
            f1[j] = (_Float16)(WL1[k] * 0.125f);
        }
        fL0[g][lane] = f0; fL1[g][lane] = f1;
    }
    __syncthreads();     // the only block-wide barrier

    const floatx4 zzero = {0.f, 0.f, 0.f, 0.f};

    const int n  = blockIdx.x*4 + g;
    const int r0 = rowstart[n];
    const int dcount = rowstart[n+1] - r0;

    float4 qa, qb;
    if (PASS == 1){
        const float* qdp = qdbuf + (size_t)n*128 + col*8;
        qa = *(const float4*)qdp;
        qb = *(const float4*)(qdp + 4);
    }
    float rz = 0.f;
    if (PASS == 2){
        float z = zbuf[n];
        rz = (z > 0.f) ? rsqrtf(z) : 0.f;
    }

    float macc0=0.f, macc1=0.f, macc2=0.f, macc3=0.f;
    float macc4=0.f, macc5=0.f, macc6=0.f, macc7=0.f;
    float zacc = 0.f;

    for (int tb = 0; tb < dcount; tb += 16){
        int slot = tb + col;
        int pc = r0 + ((slot < dcount) ? slot : (dcount-1));

        // ---- A-fragment: emb16p rows SEQUENTIAL (K=16 padded to 32) ----
        half8 ea;
        if (quad < 2){
            ea = *(const half8*)(emb16p + (size_t)pc*16 + quad*8);
        } else {
            #pragma unroll
            for (int j = 0; j < 8; ++j) ea[j] = (_Float16)0.f;
        }

        const int srcm = srcp[pc];
        const _Float16* fsrc = feats16 + (size_t)srcm*128;
        float4 yv = *(const float4*)(eattrp + (size_t)pc*4);
        const float y0 = yv.x, y1a = yv.y, y1b = yv.z, y1c = yv.w;

        half8 hx = *(const half8*)(fsrc + quad*8);
        float xs0[8];
        #pragma unroll
        for (int j = 0; j < 8; ++j) xs0[j] = (float)hx[j];
        half8 hz0 = *(const half8*)(fsrc + 32 + quad*24);
        half8 hz1 = *(const half8*)(fsrc + 32 + quad*24 + 8);
        half8 hz2 = *(const half8*)(fsrc + 32 + quad*24 + 16);
        float x1s[24];
        #pragma unroll
        for (int j = 0; j < 8; ++j){
            x1s[j]      = (float)hz0[j];
            x1s[8 + j]  = (float)hz1[j];
            x1s[16 + j] = (float)hz2[j];
        }

        // ---- GEMM1 -> ssp -> h staging ----
        floatx4 hA = MF16(ea, fW1[0][lane], zzero);
        floatx4 hB = MF16(ea, fW1[1][lane], zzero);
        floatx4 hC = MF16(ea, fW1[2][lane], zzero);
        floatx4 hD = MF16(ea, fW1[3][lane], zzero);
        #pragma unroll
        for (int r = 0; r < 4; ++r){
            stag[g][quad*4+r][   col] = (_Float16)sspf(hA[r]);
            stag[g][quad*4+r][16+col] = (_Float16)sspf(hB[r]);
            stag[g][quad*4+r][32+col] = (_Float16)sspf(hC[r]);
            stag[g][quad*4+r][48+col] = (_Float16)sspf(hD[r]);
        }
        half8 a0 = *(const half8*)&stag[g][col][quad*8];
        half8 a1 = *(const half8*)&stag[g][col][32 + quad*8];

        // ---- GEMM2: w = h @ W2 (writes overlay h; same-wave DS in-order) ----
        floatx4 wc0 = MF16(a0, fW2[ 0][lane], zzero); wc0 = MF16(a1, fW2[ 1][lane], wc0);
        floatx4 wc1 = MF16(a0, fW2[ 2][lane], zzero); wc1 = MF16(a1, fW2[ 3][lane], wc1);
        floatx4 wc2 = MF16(a0, fW2[ 4][lane], zzero); wc2 = MF16(a1, fW2[ 5][lane], wc2);
        floatx4 wc3 = MF16(a0, fW2[ 6][lane], zzero); wc3 = MF16(a1, fW2[ 7][lane], wc3);
        floatx4 wc4 = MF16(a0, fW2[ 8][lane], zzero); wc4 = MF16(a1, fW2[ 9][lane], wc4);
        floatx4 wc5 = MF16(a0, fW2[10][lane], zzero); wc5 = MF16(a1, fW2[11][lane], wc5);
        floatx4 wc6 = MF16(a0, fW2[12][lane], zzero); wc6 = MF16(a1, fW2[13][lane], wc6);
        floatx4 wc7 = MF16(a0, fW2[14][lane], zzero); wc7 = MF16(a1, fW2[15][lane], wc7);
        #pragma unroll
        for (int r = 0; r < 4; ++r){
            stag[g][quad*4+r][  0+col] = (_Float16)wc0[r];
            stag[g][quad*4+r][ 16+col] = (_Float16)wc1[r];
            stag[g][quad*4+r][ 32+col] = (_Float16)wc2[r];
            stag[g][quad*4+r][ 48+col] = (_Float16)wc3[r];
            stag[g][quad*4+r][ 64+col] = (_Float16)wc4[r];
            stag[g][quad*4+r][ 80+col] = (_Float16)wc5[r];
            stag[g][quad*4+r][ 96+col] = (_Float16)wc6[r];
            stag[g][quad*4+r][112+col] = (_Float16)wc7[r];
        }
        half8 w0h = *(const half8*)&stag[g][col][     quad*8];
        half8 w1h = *(const half8*)&stag[g][col][32 + quad*8];
        half8 w2h = *(const half8*)&stag[g][col][64 + quad*8];
        half8 w3h = *(const half8*)&stag[g][col][96 + quad*8];

        // ---- uvu: km directly in lin A-frag layout ----
        half8 fk0s0, fk0s1, fc0s0, fc0s1, fc1s0, fc1s1, fc2s0, fc2s1;
        #pragma unroll
        for (int j = 0; j < 8; ++j){
            float ww0=(float)w0h[j], ww1=(float)w1h[j];
            float ww2=(float)w2h[j], ww3=(float)w3h[j];
            float x0 = xs0[j];
            float xa = x1s[3*j], xb = x1s[3*j+1], xc = x1s[3*j+2];
            fk0s0[j] = (_Float16)(ww0 * x0 * y0);
            fk0s1[j] = (_Float16)(ww3 * (xa*y1a + xb*y1b + xc*y1c) * INV_SQRT3);
            fc0s0[j] = (_Float16)(ww1 * x0 * y1a);
            fc1s0[j] = (_Float16)(ww1 * x0 * y1b);
            fc2s0[j] = (_Float16)(ww1 * x0 * y1c);
            fc0s1[j] = (_Float16)(ww2 * xa * y0);
            fc1s1[j] = (_Float16)(ww2 * xb * y0);
            fc2s1[j] = (_Float16)(ww2 * xc * y0);
        }

        // ---- lin: k/v = km @ WL ----
        floatx4 k0a = MF16(fk0s0, fL0[0][lane], zzero); k0a = MF16(fk0s1, fL0[1][lane], k0a);
        floatx4 k0b = MF16(fk0s0, fL0[2][lane], zzero); k0b = MF16(fk0s1, fL0[3][lane], k0b);
        floatx4 kc0a = MF16(fc0s0, fL1[0][lane], zzero); kc0a = MF16(fc0s1, fL1[1][lane], kc0a);
        floatx4 kc0b = MF16(fc0s0, fL1[2][lane], zzero); kc0b = MF16(fc0s1, fL1[3][lane], kc0b);
        floatx4 kc1a = MF16(fc1s0, fL1[0][lane], zzero); kc1a = MF16(fc1s1, fL1[1][lane], kc1a);
        floatx4 kc1b = MF16(fc1s0, fL1[2][lane], zzero); kc1b = MF16(fc1s1, fL1[3][lane], kc1b);
        floatx4 kc2a = MF16(fc2s0, fL1[0][lane], zzero); kc2a = MF16(fc2s1, fL1[1][lane], kc2a);
        floatx4 kc2b = MF16(fc2s0, fL1[2][lane], zzero); kc2b = MF16(fc2s1, fL1[3][lane], kc2b);

        if (PASS == 1){
            #pragma unroll
            for (int r = 0; r < 4; ++r){
                float dd = k0a[r]*qa.x + k0b[r]*qa.y + kc0a[r]*qa.z + kc1a[r]*qa.w
                         + kc2a[r]*qb.x + kc0b[r]*qb.y + kc1b[r]*qb.z + kc2b[r]*qb.w;
                dd += __shfl_xor(dd, 1);
                dd += __shfl_xor(dd, 2);
                dd += __shfl_xor(dd, 4);
                dd += __shfl_xor(dd, 8);
                // cutoff const: diff = pos[src]-pos[src] == 0 (reference bug)
                bool valid = (tb + quad*4 + r) < dcount;
                float ev = valid ? (0.9048374180359595f * __expf(dd)) : 0.f;
                zacc += ev;
                if (col == 0 && valid)
                    cfbuf[r0 + tb + quad*4 + r] = sqrtf(ev);
            }
        } else {
            float coef0, coef1, coef2, coef3;
            #pragma unroll
            for (int r = 0; r < 4; ++r){
                int sl = tb + quad*4 + r;
                float cf = (sl < dcount) ? cfbuf[r0 + sl] : 0.f;
                if (r==0) coef0 = cf; else if (r==1) coef1 = cf;
                else if (r==2) coef2 = cf; else coef3 = cf;
            }
            macc0 += coef0*k0a[0] + coef1*k0a[1] + coef2*k0a[2] + coef3*k0a[3];
            macc1 += coef0*k0b[0] + coef1*k0b[1] + coef2*k0b[2] + coef3*k0b[3];
            macc2 += coef0*kc0a[0] + coef1*kc0a[1] + coef2*kc0a[2] + coef3*kc0a[3];
            macc3 += coef0*kc1a[0] + coef1*kc1a[1] + coef2*kc1a[2] + coef3*kc1a[3];
            macc4 += coef0*kc2a[0] + coef1*kc2a[1] + coef2*kc2a[2] + coef3*kc2a[3];
            macc5 += coef0*kc0b[0] + coef1*kc0b[1] + coef2*kc0b[2] + coef3*kc0b[3];
            macc6 += coef0*kc1b[0] + coef1*kc1b[1] + coef2*kc1b[2] + coef3*kc1b[3];
            macc7 += coef0*kc2b[0] + coef1*kc2b[1] + coef2*kc2b[2] + coef3*kc2b[3];
        }
    }

    if (PASS == 1){
        float z = zacc;
        z += __shfl_xor(z, 16); z += __shfl_xor(z, 32);
        if (lane == 0) zbuf[n] = z;
    } else {
        macc0 += __shfl_xor(macc0, 16); macc0 += __shfl_xor(macc0, 32);
        macc1 += __shfl_xor(macc1, 16); macc1 += __shfl_xor(macc1, 32);
        macc2 += __shfl_xor(macc2, 16); macc2 += __shfl_xor(macc2, 32);
        macc3 += __shfl_xor(macc3, 16); macc3 += __shfl_xor(macc3, 32);
        macc4 += __shfl_xor(macc4, 16); macc4 += __shfl_xor(macc4, 32);
        macc5 += __shfl_xor(macc5, 16); macc5 += __shfl_xor(macc5, 32);
        macc6 += __shfl_xor(macc6, 16); macc6 += __shfl_xor(macc6, 32);
        macc7 += __shfl_xor(macc7, 16); macc7 += __shfl_xor(macc7, 32);
        if (lane < 16){
            float* op = out + (size_t)n*128;
            op[col]                 += macc0 * rz;
            op[col + 16]            += macc1 * rz;
            op[32 + 3*col + 0]      += macc2 * rz;
            op[32 + 3*col + 1]      += macc3 * rz;
            op[32 + 3*col + 2]      += macc4 * rz;
            op[32 + 3*(col+16) + 0] += macc5 * rz;
            op[32 + 3*(col+16) + 1] += macc6 * rz;
            op[32 + 3*(col+16) + 2] += macc7 * rz;
        }
    }
}

extern "C" void kernel_launch(void* const* d_in, const int* in_sizes, int n_in,
                              void* d_out, int out_size, void* d_ws, size_t ws_size,
                              hipStream_t stream)
{
    const float* feats = (const float*)d_in[0];
    const float* attrs = (const float*)d_in[1];
    const float* emb   = (const float*)d_in[2];
    const float* eattr = (const float*)d_in[3];
    // d_in[4] positions: unused (reference computes positions[src]-positions[src] == 0)
    const float* Wq0  = (const float*)d_in[5];
    const float* Wq1  = (const float*)d_in[6];
    const float* Wk1  = (const float*)d_in[7];
    const float* Wk2  = (const float*)d_in[8];
    const float* Wv1  = (const float*)d_in[9];
    const float* Wv2  = (const float*)d_in[10];
    const float* Wlk0 = (const float*)d_in[11];
    const float* Wlk1 = (const float*)d_in[12];
    const float* Wlv0 = (const float*)d_in[13];
    const float* Wlv1 = (const float*)d_in[14];
    const float* Wd0  = (const float*)d_in[15];
    const float* Wd1  = (const float*)d_in[16];
    const float* Ws0  = (const float*)d_in[17];
    const float* Ws1  = (const float*)d_in[18];
    const int*   eidx = (const int*)d_in[19];

    float* out   = (float*)d_out;
    float* qdbuf = (float*)d_ws;                        // N*128 (permuted qd)
    int*   degb  = (int*)(qdbuf + (size_t)N_NODES*128); // N
    int*   rowst = degb + N_NODES;                      // N+1
    int*   curs  = rowst + N_NODES + 1;                 // N
    float* cfbuf = (float*)(curs + N_NODES);            // E
    float* zbuf  = cfbuf + N_EDGES;                     // N
    float* eattrp = zbuf + N_NODES;                     // E*4 floats (CSR order)
    int*   srcp  = (int*)(eattrp + (size_t)N_EDGES*4);  // E (CSR order)
    _Float16* feats16 = (_Float16*)(srcp + N_EDGES);    // N*128 halves
    _Float16* emb16p  = feats16 + (size_t)N_NODES*128;  // E*16 halves (CSR order)

    hipMemsetAsync(degb, 0, N_NODES*sizeof(int), stream);
    node_kernel<<<N_NODES/4, 256, 0, stream>>>(feats, attrs, Wq0, Wq1, Wd0, Wd1,
                                               Ws0, Ws1, qdbuf, out);
    convert_kernel<<<1024, 256, 0, stream>>>(feats, feats16);
    count_kernel<<<N_EDGES/256, 256, 0, stream>>>(eidx, degb);
    scan_kernel<<<1, 256, 0, stream>>>(degb, rowst, curs);
    scatter_kernel<<<N_EDGES/256, 256, 0, stream>>>(eidx, emb, eattr, curs,
                                                    srcp, emb16p, eattrp);
    edge_pass<1><<<N_NODES/4, 256, 0, stream>>>(feats16, emb16p, eattrp, srcp,
                                                Wk1, Wk2, Wlk0, Wlk1,
                                                qdbuf, rowst,
                                                cfbuf, zbuf, out);
    edge_pass<2><<<N_NODES/4, 256, 0, stream>>>(feats16, emb16p, eattrp, srcp,
                                                Wv1, Wv2, Wlv0, Wlv1,
                                                qdbuf, rowst,
                                                cfbuf, zbuf, out);
}